// Round 11
// baseline (126.520 us; speedup 1.0000x reference)
//
#include <hip/hip_runtime.h>
#include <hip/hip_bf16.h>

#define NN 192
#define NBA 3
#define NH 8
#define ND 10
#define NE_ (NN*NN)          // 36864
#define NE2 (NE_/2)          // 18432
#define OUTC 202             // 10 + 8*16 + 8*8

typedef unsigned int u32;
typedef unsigned short u16;
typedef __attribute__((ext_vector_type(2))) _Float16 h2v;
typedef __attribute__((ext_vector_type(8))) _Float16 f16x8;
typedef __attribute__((ext_vector_type(4))) float f32x4;

// ---- workspace layout (float-sized slots) ----
static const size_t OFF_ETI0  = 0;                        // [8][2*NE2] u32: groups of 8 (4 et pairs, 4 et5 pairs)
static const size_t OFF_ETI1  = OFF_ETI0  + 294912;
static const size_t OFF_FT0P  = OFF_ETI1  + 294912;       // [8][4][NE2] u32 half2
static const size_t OFF_FT1P  = OFF_FT0P  + 589824;       // [8][2][NE2]
static const size_t OFF_EAP   = OFF_FT1P  + 294912;       // [192][NE2] u32 half2 exp(adj)
static const size_t OFF_XH1   = OFF_EAP   + 3538944;      // [3][192][128] f32
static const size_t OFF_EINF  = OFF_XH1   + 73728;        // [3][192][192]
static const size_t OFF_ES0   = OFF_EINF  + 110592;       // [3][8][192] u32 half2(es,es)
static const size_t OFF_ES50  = OFF_ES0   + 4608;
static const size_t OFF_ES1   = OFF_ES50  + 4608;
static const size_t OFF_ES51  = OFF_ES1   + 4608;
static const size_t OFF_WT1   = OFF_ES51  + 4608;         // [3][8][128] f32
static const size_t OFF_PART  = OFF_WT1   + 3072;         // [3][64][12][8][FE+1][16]
static const size_t OFF_RED   = OFF_PART  + 1474560;      // [3][96][80] reduced partials
static const size_t OFF_F2    = OFF_RED   + 23040;        // [3][8*F][192] transposed
static const size_t OFF_S2    = OFF_F2    + 73728;
static const size_t OFF_T2    = OFF_S2    + 4608;
static const size_t OFF_TE    = OFF_T2    + 4608;
static const size_t OFF_CS    = OFF_TE    + 4608;         // [3][192]
// total ~6.82M floats ~27.3 MB

__device__ __forceinline__ u32 h2u(h2v h) { union { h2v h; u32 u; } c; c.h = h; return c.u; }
__device__ __forceinline__ h2v u2h(u32 u) { union { u32 u; h2v h; } c; c.u = u; return c.h; }
__device__ __forceinline__ u32 packh(float a, float b) {
    h2v h; h.x = (_Float16)a; h.y = (_Float16)b; return h2u(h);
}

// ---------------- K_PRE: all attr-independent preprocessing, one launch ----------------
__global__ __launch_bounds__(256) void k_pre(
    const float* __restrict__ E, const float* __restrict__ adj,
    const float* __restrict__ X,
    const float* __restrict__ we0, const float* __restrict__ aen0,
    const float* __restrict__ we1, const float* __restrict__ aen1,
    const float* __restrict__ wn0, const float* __restrict__ aes0,
    const float* __restrict__ wn1, const float* __restrict__ aes1,
    u32* __restrict__ etI0, u32* __restrict__ etI1,
    u32* __restrict__ ft0P, u32* __restrict__ ft1P,
    u32* __restrict__ eaP,
    u32* __restrict__ es0, u32* __restrict__ es50,
    float* __restrict__ wt1)
{
    int b = blockIdx.x, tid = threadIdx.x;
    if (b < 72) {
        __shared__ float w0s[96], a0s[32], w1s[512], a1s[16];
        for (int i = tid; i < 96;  i += 256) w0s[i] = we0[i];
        for (int i = tid; i < 32;  i += 256) a0s[i] = aen0[i];
        for (int i = tid; i < 512; i += 256) w1s[i] = we1[i];
        for (int i = tid; i < 16;  i += 256) a1s[i] = aen1[i];
        __syncthreads();
        int ep = b*256 + tid;            // e-pair index
        int gslot = ((ep >> 2) << 3) + (ep & 3);   // interleaved group slot
        int e0 = 2*ep;
        float2 E0 = *(const float2*)(E + e0);
        float2 E1 = *(const float2*)(E + NE_ + e0);
        float2 E2 = *(const float2*)(E + 2*NE_ + e0);
        float fa[32], fb[32];
        #pragma unroll
        for (int h = 0; h < 8; h++) {
            float ta = 0.f, tb = 0.f;
            #pragma unroll
            for (int f = 0; f < 4; f++) {
                float wa = w0s[h*12+f], wb = w0s[h*12+4+f], wc = w0s[h*12+8+f];
                float va = E0.x*wa + E1.x*wb + E2.x*wc;
                float vb = E0.y*wa + E1.y*wb + E2.y*wc;
                fa[h*4+f] = va; fb[h*4+f] = vb;
                ft0P[(size_t)(h*4+f)*NE2 + ep] = packh(va, vb);
                ta += va * a0s[h*4+f];
                tb += vb * a0s[h*4+f];
            }
            etI0[(size_t)h*2*NE2 + gslot]     = packh(__expf(ta), __expf(tb));
            etI0[(size_t)h*2*NE2 + gslot + 4] = packh(__expf(0.2f*ta), __expf(0.2f*tb));
        }
        #pragma unroll
        for (int h = 0; h < 8; h++) {
            float aa = 0.f, ba = 0.f, ab = 0.f, bb = 0.f;
            #pragma unroll
            for (int d = 0; d < 32; d++) {
                float w0 = w1s[(h*32+d)*2], w1 = w1s[(h*32+d)*2+1];
                aa += fa[d] * w0;  ba += fa[d] * w1;
                ab += fb[d] * w0;  bb += fb[d] * w1;
            }
            ft1P[(size_t)(h*2+0)*NE2 + ep] = packh(aa, ab);
            ft1P[(size_t)(h*2+1)*NE2 + ep] = packh(ba, bb);
            float ta = aa*a1s[h*2] + ba*a1s[h*2+1];
            float tb = ab*a1s[h*2] + bb*a1s[h*2+1];
            etI1[(size_t)h*2*NE2 + gslot]     = packh(__expf(ta), __expf(tb));
            etI1[(size_t)h*2*NE2 + gslot + 4] = packh(__expf(0.2f*ta), __expf(0.2f*tb));
        }
    } else if (b < 1800) {
        int idx = (b - 72)*256 + tid;      // [0, 442368)
        int n = idx / 2304, c8 = idx % 2304;
        const float* ap = adj + (size_t)n*NE_ + c8*16;
        u32 o[8];
        #pragma unroll
        for (int q = 0; q < 4; q++) {
            float4 v = *(const float4*)(ap + q*4);
            o[2*q]   = packh(__expf(v.x), __expf(v.y));
            o[2*q+1] = packh(__expf(v.z), __expf(v.w));
        }
        u32* dst = eaP + (size_t)n*NE2 + c8*8;
        *(uint4*)(dst)     = make_uint4(o[0], o[1], o[2], o[3]);
        *(uint4*)(dst + 4) = make_uint4(o[4], o[5], o[6], o[7]);
    } else if (b == 1800) {
        for (int v = tid; v < 3072; v += 256) {
            int a = v >> 10, rem = v & 1023, h = rem >> 7, d = rem & 127;
            float w = 0.f;
            #pragma unroll
            for (int f = 0; f < 8; f++)
                w += wn1[(((size_t)a*NH + h)*128 + d)*8 + f] * aes1[h*8 + f];
            wt1[v] = w;
        }
    } else {
        int ah = b - 1801;
        int a = ah / NH, h = ah % NH;
        __shared__ float wt0[ND];
        if (tid < ND) {
            float w = 0.f;
            #pragma unroll
            for (int f = 0; f < 16; f++)
                w += wn0[(((size_t)a*NH + h)*ND + tid)*16 + f] * aes0[h*16 + f];
            wt0[tid] = w;
        }
        __syncthreads();
        if (tid < NN) {
            float s = 0.f;
            #pragma unroll
            for (int d = 0; d < ND; d++) s += X[tid*ND + d] * wt0[d];
            es0 [ah*NN + tid] = packh(__expf(s), __expf(s));
            es50[ah*NN + tid] = packh(__expf(0.2f*s), __expf(0.2f*s));
        }
    }
}

// ---------------- K1: e2n attention, fp16 pk-math + f16 MFMA + LDS-staged ea ----------------
template<int FE>
__global__ __launch_bounds__(512, 3) void k_att3(
    const u32* __restrict__ es_,   // [A][H][N] half2(es,es)
    const u32* __restrict__ es5_,  // [A][H][N]
    const u32* __restrict__ etI,   // [H][NE2/4 groups][8]: 4 et pairs + 4 et5 pairs
    const u32* __restrict__ feP,   // [H][FE][NE2]
    const u32* __restrict__ eaP,   // [N][NE2]
    float* __restrict__ part)      // [A][S][12][H][FE+1][16]
{
    constexpr int S = 64, EPB = NE_/S, TILES = EPB/32;   // EPB=576, TILES=18
    constexpr int EP2 = EPB/2;                            // 288 u32 per row
    constexpr int ROWP = EP2 + 4;                         // padded row
    constexpr size_t PA = (size_t)S*12*NH*(FE+1)*16;
    __shared__ u32 sea[16*ROWP];                          // 18.7 KB

    int h = threadIdx.x >> 6, lane = threadIdx.x & 63;
    int fr = lane & 15, kg = lane >> 4;
    int split = blockIdx.x, ntile = blockIdx.y;
    int nm = ntile*16 + fr;
    int p0 = split*EP2;

    // cooperative stage: 512 threads, 16 rows x 288 u32
    {
        int r = threadIdx.x >> 5, c0 = threadIdx.x & 31;
        const u32* src = eaP + (size_t)(ntile*16 + r)*NE2 + p0;
        #pragma unroll
        for (int i = 0; i < 9; i++)
            sea[r*ROWP + c0 + i*32] = src[c0 + i*32];
    }

    h2v esh[NBA], es5h[NBA];
    #pragma unroll
    for (int a = 0; a < NBA; a++) {
        esh[a]  = u2h(es_ [(a*NH + h)*NN + nm]);
        es5h[a] = u2h(es5_[(a*NH + h)*NN + nm]);
    }

    const u32* etg = etI + (size_t)h*2*NE2 + ((size_t)split*72 + kg)*8;
    const u32* fp  = feP + ((size_t)h*FE + (fr < FE ? fr : 0))*NE2 + p0 + kg*4;
    u32 bfill = (fr == FE) ? 0x3C003C00u : 0u;   // fp16 1.0 pair / 0
    uint4 bc = make_uint4(bfill, bfill, bfill, bfill);

    f32x4 acc[NBA];
    #pragma unroll
    for (int a = 0; a < NBA; a++) acc[a] = (f32x4){0.f, 0.f, 0.f, 0.f};

    __syncthreads();

    const u32* seap = sea + fr*ROWP + kg*4;
    #pragma unroll 2
    for (int t = 0; t < TILES; t++) {
        uint4 etq  = *(const uint4*)(etg + t*32);
        uint4 et5q = *(const uint4*)(etg + t*32 + 4);
        uint4 eaq  = *(const uint4*)(seap + t*16);
        uint4 bq = bc;
        if (fr < FE) bq = *(const uint4*)(fp + t*16);
        union { uint4 u; f16x8 v; } B; B.u = bq;

        u32 etw[4]  = {etq.x,  etq.y,  etq.z,  etq.w};
        u32 et5w[4] = {et5q.x, et5q.y, et5q.z, et5q.w};
        u32 eaw[4]  = {eaq.x,  eaq.y,  eaq.z,  eaq.w};
        h2v g1[4], g2[4];
        #pragma unroll
        for (int p = 0; p < 4; p++) {
            h2v ea = u2h(eaw[p]);
            g1[p] = u2h(etw[p])  * ea;
            g2[p] = u2h(et5w[p]) * ea;
        }
        #pragma unroll
        for (int a = 0; a < NBA; a++) {
            union { uint4 u; f16x8 v; } A;
            u32 aw[4];
            #pragma unroll
            for (int p = 0; p < 4; p++) {
                h2v wv = __builtin_elementwise_max(esh[a] * g1[p], es5h[a] * g2[p]);
                aw[p] = h2u(wv);
            }
            A.u = make_uint4(aw[0], aw[1], aw[2], aw[3]);
            acc[a] = __builtin_amdgcn_mfma_f32_16x16x32_f16(A.v, B.v, acc[a], 0, 0, 0);
        }
    }

    if (fr <= FE) {
        float* pp = part + ((((size_t)split*12 + ntile)*NH + h)*(FE+1) + fr)*16 + kg*4;
        #pragma unroll
        for (int a = 0; a < NBA; a++)
            *(f32x4*)(pp + (size_t)a*PA) = acc[a];
    }
}

// ---------------- K1b: coalesced reduction of part over S ----------------
template<int FE>
__global__ __launch_bounds__(256) void k_red(
    const float* __restrict__ part, float* __restrict__ red)
{
    constexpr int S = 64, W = (FE+1)*16;
    constexpr size_t SSTR = (size_t)12*NH*W;
    constexpr size_t PA = (size_t)S*SSTR;
    int nt = blockIdx.x >> 3, h = blockIdx.x & 7;
    int t = threadIdx.x;
    if (t >= NBA*W) return;
    int a = t / W, i = t % W;
    const float* pp = part + (size_t)a*PA + ((size_t)nt*NH + h)*W + i;
    float v = 0.f;
    #pragma unroll 8
    for (int s = 0; s < S; s++) v += pp[(size_t)s*SSTR];
    red[((size_t)a*96 + nt*8 + h)*W + i] = v;
}

// ---------------- K2: f2T, s2, t2 from reduced partials (grid.y = attr) ----------------
template<int DIN, int F, int FE>
__global__ __launch_bounds__(256) void k_mid(
    const float* __restrict__ Xh, int xstride,
    const float* __restrict__ wn,   // [A][H][DIN][F]
    const float* __restrict__ be,   // [H][FE]
    const float* __restrict__ wct,  // [H][F+FE][F]
    const float* __restrict__ bct,  // [H][F]
    const float* __restrict__ asf,  // [A][H][F]
    const float* __restrict__ anf,  // [A][H][F]
    const float* __restrict__ red,  // [A][96][(FE+1)*16]
    float* __restrict__ f2T,        // [A][H*F][N] transposed
    float* __restrict__ s2, float* __restrict__ t2)
{
    constexpr int DCT = F + FE, W = (FE+1)*16;
    int n = blockIdx.x, attr = blockIdx.y;
    int h = threadIdx.x >> 5, lane = threadIdx.x & 31;
    const float* Xp = Xh + (size_t)attr*xstride;
    const float* wnp = wn + (size_t)attr*NH*DIN*F;
    float v = 0.f;
    if (lane <= FE)
        v = red[((size_t)attr*96 + (n>>4)*8 + h)*W + lane*16 + (n & 15)];
    float den = __shfl(v, FE, 32);
    float nfe = (lane < FE) ? v/den + be[h*FE+lane] : 0.f;
    float fv = 0.f;
    if (lane < F) {
        for (int d = 0; d < DIN; d++) fv += Xp[n*DIN+d] * wnp[(h*DIN+d)*F+lane];
    }
    __shared__ float c[NH][DCT];
    if (lane < F)  c[h][lane]     = fv;
    if (lane < FE) c[h][F + lane] = nfe;
    __syncthreads();
    float f2v = 0.f;
    if (lane < F) {
        f2v = bct[h*F+lane];
        #pragma unroll
        for (int d = 0; d < DCT; d++) f2v += c[h][d] * wct[(h*DCT+d)*F+lane];
        f2T[(size_t)attr*NH*F*NN + (size_t)(h*F+lane)*NN + n] = f2v;
    }
    float s2p = (lane < F) ? f2v * asf[attr*NH*F + h*F+lane] : 0.f;
    float t2p = (lane < F) ? f2v * anf[attr*NH*F + h*F+lane] : 0.f;
    #pragma unroll
    for (int m = 1; m < 32; m <<= 1) { s2p += __shfl_xor(s2p, m); t2p += __shfl_xor(t2p, m); }
    if (lane == 0) { s2[attr*NH*NN + h*NN+n] = s2p; t2[attr*NH*NN + h*NN+n] = t2p; }
}

// ---------------- K3: tE[h,k] = sum_m t2[h,m]*Einfo[m,k]; colsum (grid.y=attr) ----------------
__global__ __launch_bounds__(192) void k_te(
    const float* __restrict__ Einfo, size_t estride,
    const float* __restrict__ t2,
    float* __restrict__ tE, float* __restrict__ cs)
{
    int h = blockIdx.x, attr = blockIdx.y, k = threadIdx.x;
    const float* Ep = Einfo + (size_t)attr*estride;
    float a = 0.f, c = 0.f;
    #pragma unroll 4
    for (int m = 0; m < NN; m++) {
        float ev = Ep[m*NN + k];
        a += t2[attr*NH*NN + h*NN + m] * ev;
        c += ev;
    }
    tE[attr*NH*NN + h*NN + k] = a;
    if (h == 0) cs[attr*NN + k] = c;
}

// ---------------- K4: att2 rows, nf, outputs (grid.y = attr); L0 also emits es1 ----------------
template<int F, int LAYER>
__global__ __launch_bounds__(256) void k_out(
    const float* __restrict__ A,    // [A][N][N]
    const float* __restrict__ s2, const float* __restrict__ tE,
    const float* __restrict__ cs, const float* __restrict__ f2T,
    const float* __restrict__ bn,   // [A][H][F]
    const float* __restrict__ X,
    float* __restrict__ out,
    float* __restrict__ xh1, float* __restrict__ einfo,
    const float* __restrict__ wt1,  // [A][H][128]
    u32* __restrict__ es1, u32* __restrict__ es51)
{
    int n = blockIdx.x, attr = blockIdx.y;
    int h = threadIdx.x >> 5, lane = threadIdx.x & 31;
    const float* Aattr = A + (size_t)attr*NE_;
    float s2h = s2[attr*NH*NN + h*NN + n];
    float z[6];
    #pragma unroll
    for (int c6 = 0; c6 < 6; c6++) {
        int k = lane + 32*c6;
        float d2v = s2h * cs[attr*NN + k] + tE[attr*NH*NN + h*NN + k];
        z[c6] = fmaxf(d2v, 0.2f*d2v) + Aattr[n*NN + k];
    }
    float mx = z[0];
    #pragma unroll
    for (int c6 = 1; c6 < 6; c6++) mx = fmaxf(mx, z[c6]);
    #pragma unroll
    for (int m = 1; m < 32; m <<= 1) mx = fmaxf(mx, __shfl_xor(mx, m));
    float w[6], den = 0.f;
    #pragma unroll
    for (int c6 = 0; c6 < 6; c6++) { w[c6] = __expf(z[c6] - mx); den += w[c6]; }
    #pragma unroll
    for (int m = 1; m < 32; m <<= 1) den += __shfl_xor(den, m);
    __shared__ float attL[NH][NN];
    __shared__ float xrow[128];
    #pragma unroll
    for (int c6 = 0; c6 < 6; c6++) attL[h][lane + 32*c6] = w[c6];
    __syncthreads();
    float r = 0.f;
    if (lane < F) {
        const float* frow = f2T + (size_t)attr*NH*F*NN + (size_t)(h*F+lane)*NN;
        #pragma unroll 4
        for (int k4 = 0; k4 < NN/4; k4++) {
            float4 aq = *(const float4*)(&attL[h][k4*4]);
            float4 fq = *(const float4*)(frow + k4*4);
            r += aq.x*fq.x + aq.y*fq.y + aq.z*fq.z + aq.w*fq.w;
        }
        r = r/den + bn[attr*NH*F + h*F + lane];
        r = r > 0.f ? r : __expf(r) - 1.f;   // elu
        out[((size_t)n*NBA + attr)*OUTC + (LAYER == 0 ? 10 : 138) + h*F + lane] = r;
        if (LAYER == 0) {
            xh1[(size_t)attr*NN*128 + n*128 + h*16 + lane] = r;
            xrow[h*16 + lane] = r;
        }
    }
    if (LAYER == 0 && h == 7) {
        #pragma unroll
        for (int c6 = 0; c6 < 6; c6++)
            einfo[(size_t)attr*NE_ + n*NN + lane + 32*c6] = w[c6] / den;
    }
    if (LAYER == 0 && h == 0 && lane < ND)
        out[((size_t)n*NBA + attr)*OUTC + lane] = X[n*ND + lane];
    if (LAYER == 0) {
        __syncthreads();
        float sp = 0.f;
        const float* wp = wt1 + ((size_t)attr*NH + h)*128;
        #pragma unroll
        for (int q = 0; q < 4; q++) sp += xrow[lane*4+q] * wp[lane*4+q];
        #pragma unroll
        for (int m = 1; m < 32; m <<= 1) sp += __shfl_xor(sp, m);
        if (lane == 0) {
            es1 [(attr*NH + h)*NN + n] = packh(__expf(sp), __expf(sp));
            es51[(attr*NH + h)*NN + n] = packh(__expf(0.2f*sp), __expf(0.2f*sp));
        }
    }
}

extern "C" void kernel_launch(void* const* d_in, const int* in_sizes, int n_in,
                              void* d_out, int out_size, void* d_ws, size_t ws_size,
                              hipStream_t stream) {
    const float* X    = (const float*)d_in[0];
    const float* A    = (const float*)d_in[1];
    const float* E    = (const float*)d_in[2];
    const float* adj  = (const float*)d_in[3];
    const float* w_n0 = (const float*)d_in[4];
    const float* b_n0 = (const float*)d_in[5];
    const float* as0  = (const float*)d_in[6];
    const float* an0  = (const float*)d_in[7];
    const float* w_n1 = (const float*)d_in[8];
    const float* b_n1 = (const float*)d_in[9];
    const float* as1  = (const float*)d_in[10];
    const float* an1  = (const float*)d_in[11];
    const float* w_e0 = (const float*)d_in[12];
    const float* b_e0 = (const float*)d_in[13];
    const float* w_ct0= (const float*)d_in[14];
    const float* b_ct0= (const float*)d_in[15];
    const float* aes0 = (const float*)d_in[16];
    const float* aen0 = (const float*)d_in[17];
    const float* w_e1 = (const float*)d_in[18];
    const float* b_e1 = (const float*)d_in[19];
    const float* w_ct1= (const float*)d_in[20];
    const float* b_ct1= (const float*)d_in[21];
    const float* aes1 = (const float*)d_in[22];
    const float* aen1 = (const float*)d_in[23];

    float* w      = (float*)d_ws;
    u32* etI0  = (u32*)(w + OFF_ETI0);
    u32* etI1  = (u32*)(w + OFF_ETI1);
    u32* ft0P  = (u32*)(w + OFF_FT0P);
    u32* ft1P  = (u32*)(w + OFF_FT1P);
    u32* eaP   = (u32*)(w + OFF_EAP);
    float* xh1   = w + OFF_XH1;
    float* einfo = w + OFF_EINF;
    u32* es0   = (u32*)(w + OFF_ES0);
    u32* es50  = (u32*)(w + OFF_ES50);
    u32* es1   = (u32*)(w + OFF_ES1);
    u32* es51  = (u32*)(w + OFF_ES51);
    float* wt1   = w + OFF_WT1;
    float* part  = w + OFF_PART;
    float* red   = w + OFF_RED;
    float* f2T   = w + OFF_F2;
    float* s2    = w + OFF_S2;
    float* t2    = w + OFF_T2;
    float* tE    = w + OFF_TE;
    float* cs    = w + OFF_CS;
    float* out   = (float*)d_out;

    k_pre<<<dim3(1825), dim3(256), 0, stream>>>(
        E, adj, X, w_e0, aen0, w_e1, aen1, w_n0, aes0, w_n1, aes1,
        etI0, etI1, ft0P, ft1P, eaP, es0, es50, wt1);

    // ---- layer 0 ----
    k_att3<4><<<dim3(64,12), dim3(512), 0, stream>>>(
        es0, es50, etI0, ft0P, eaP, part);
    k_red<4><<<dim3(96), dim3(256), 0, stream>>>(part, red);
    k_mid<10,16,4><<<dim3(NN,NBA), dim3(256), 0, stream>>>(
        X, 0, w_n0, b_e0, w_ct0, b_ct0, as0, an0, red, f2T, s2, t2);
    k_te<<<dim3(8,NBA), dim3(192), 0, stream>>>(E, (size_t)NE_, t2, tE, cs);
    k_out<16,0><<<dim3(NN,NBA), dim3(256), 0, stream>>>(
        A, s2, tE, cs, f2T, b_n0, X, out, xh1, einfo, wt1, es1, es51);

    // ---- layer 1 ----
    k_att3<2><<<dim3(64,12), dim3(512), 0, stream>>>(
        es1, es51, etI1, ft1P, eaP, part);
    k_red<2><<<dim3(96), dim3(256), 0, stream>>>(part, red);
    k_mid<128,8,2><<<dim3(NN,NBA), dim3(256), 0, stream>>>(
        xh1, NN*128, w_n1, b_e1, w_ct1, b_ct1, as1, an1, red, f2T, s2, t2);
    k_te<<<dim3(8,NBA), dim3(192), 0, stream>>>(einfo, (size_t)NE_, t2, tE, cs);
    k_out<8,1><<<dim3(NN,NBA), dim3(256), 0, stream>>>(
        A, s2, tE, cs, f2T, b_n1, X, out, xh1, einfo, wt1, es1, es51);
}

// Round 12
// 99.655 us; speedup vs baseline: 1.2696x; 1.2696x over previous
//
#include <hip/hip_runtime.h>
#include <hip/hip_bf16.h>

#define NN 192
#define NBA 3
#define NH 8
#define ND 10
#define NE_ (NN*NN)          // 36864
#define NE2 (NE_/2)          // 18432
#define OUTC 202             // 10 + 8*16 + 8*8

typedef unsigned int u32;
typedef unsigned short u16;
typedef __attribute__((ext_vector_type(2))) _Float16 h2v;
typedef __attribute__((ext_vector_type(8))) _Float16 f16x8;
typedef __attribute__((ext_vector_type(4))) float f32x4;

// ---- workspace layout (float-sized slots) ----
static const size_t OFF_ETI0  = 0;                        // [8][2*NE2] u32: groups of 8 (4 et pairs, 4 et5 pairs)
static const size_t OFF_ETI1  = OFF_ETI0  + 294912;
static const size_t OFF_FT0P  = OFF_ETI1  + 294912;       // [8][4][NE2] u32 half2
static const size_t OFF_FT1P  = OFF_FT0P  + 589824;       // [8][2][NE2]
static const size_t OFF_EAP   = OFF_FT1P  + 294912;       // [192][NE2] u32 half2 exp(adj)
static const size_t OFF_XH1   = OFF_EAP   + 3538944;      // [3][192][128] f32
static const size_t OFF_EINF  = OFF_XH1   + 73728;        // [3][192][192]
static const size_t OFF_ES0   = OFF_EINF  + 110592;       // [3][8][192] u32 half2(es,es)
static const size_t OFF_ES50  = OFF_ES0   + 4608;
static const size_t OFF_ES1   = OFF_ES50  + 4608;
static const size_t OFF_ES51  = OFF_ES1   + 4608;
static const size_t OFF_WT1   = OFF_ES51  + 4608;         // [3][8][128] f32
static const size_t OFF_PART  = OFF_WT1   + 3072;         // [3][64][12][8][FE+1][16]
static const size_t OFF_RED   = OFF_PART  + 1474560;      // [3][96][80] reduced partials
static const size_t OFF_F2    = OFF_RED   + 23040;        // [3][8][192][16]
static const size_t OFF_S2    = OFF_F2    + 73728;
static const size_t OFF_T2    = OFF_S2    + 4608;
static const size_t OFF_TEP   = OFF_T2    + 4608;         // [3][8][4][192] partial tE
static const size_t OFF_CSP   = OFF_TEP   + 18432;        // [3][4][192]
// total ~6.84M floats ~27.4 MB

__device__ __forceinline__ u32 h2u(h2v h) { union { h2v h; u32 u; } c; c.h = h; return c.u; }
__device__ __forceinline__ h2v u2h(u32 u) { union { u32 u; h2v h; } c; c.u = u; return c.h; }
__device__ __forceinline__ u32 packh(float a, float b) {
    h2v h; h.x = (_Float16)a; h.y = (_Float16)b; return h2u(h);
}

// ---------------- K_PRE: all attr-independent preprocessing, one launch ----------------
__global__ __launch_bounds__(256) void k_pre(
    const float* __restrict__ E, const float* __restrict__ adj,
    const float* __restrict__ X,
    const float* __restrict__ we0, const float* __restrict__ aen0,
    const float* __restrict__ we1, const float* __restrict__ aen1,
    const float* __restrict__ wn0, const float* __restrict__ aes0,
    const float* __restrict__ wn1, const float* __restrict__ aes1,
    u32* __restrict__ etI0, u32* __restrict__ etI1,
    u32* __restrict__ ft0P, u32* __restrict__ ft1P,
    u32* __restrict__ eaP,
    u32* __restrict__ es0, u32* __restrict__ es50,
    float* __restrict__ wt1)
{
    int b = blockIdx.x, tid = threadIdx.x;
    if (b < 72) {
        __shared__ float w0s[96], a0s[32], w1s[512], a1s[16];
        for (int i = tid; i < 96;  i += 256) w0s[i] = we0[i];
        for (int i = tid; i < 32;  i += 256) a0s[i] = aen0[i];
        for (int i = tid; i < 512; i += 256) w1s[i] = we1[i];
        for (int i = tid; i < 16;  i += 256) a1s[i] = aen1[i];
        __syncthreads();
        int ep = b*256 + tid;            // e-pair index
        int gslot = ((ep >> 2) << 3) + (ep & 3);   // interleaved group slot
        int e0 = 2*ep;
        float2 E0 = *(const float2*)(E + e0);
        float2 E1 = *(const float2*)(E + NE_ + e0);
        float2 E2 = *(const float2*)(E + 2*NE_ + e0);
        float fa[32], fb[32];
        #pragma unroll
        for (int h = 0; h < 8; h++) {
            float ta = 0.f, tb = 0.f;
            #pragma unroll
            for (int f = 0; f < 4; f++) {
                float wa = w0s[h*12+f], wb = w0s[h*12+4+f], wc = w0s[h*12+8+f];
                float va = E0.x*wa + E1.x*wb + E2.x*wc;
                float vb = E0.y*wa + E1.y*wb + E2.y*wc;
                fa[h*4+f] = va; fb[h*4+f] = vb;
                ft0P[(size_t)(h*4+f)*NE2 + ep] = packh(va, vb);
                ta += va * a0s[h*4+f];
                tb += vb * a0s[h*4+f];
            }
            etI0[(size_t)h*2*NE2 + gslot]     = packh(__expf(ta), __expf(tb));
            etI0[(size_t)h*2*NE2 + gslot + 4] = packh(__expf(0.2f*ta), __expf(0.2f*tb));
        }
        #pragma unroll
        for (int h = 0; h < 8; h++) {
            float aa = 0.f, ba = 0.f, ab = 0.f, bb = 0.f;
            #pragma unroll
            for (int d = 0; d < 32; d++) {
                float w0 = w1s[(h*32+d)*2], w1 = w1s[(h*32+d)*2+1];
                aa += fa[d] * w0;  ba += fa[d] * w1;
                ab += fb[d] * w0;  bb += fb[d] * w1;
            }
            ft1P[(size_t)(h*2+0)*NE2 + ep] = packh(aa, ab);
            ft1P[(size_t)(h*2+1)*NE2 + ep] = packh(ba, bb);
            float ta = aa*a1s[h*2] + ba*a1s[h*2+1];
            float tb = ab*a1s[h*2] + bb*a1s[h*2+1];
            etI1[(size_t)h*2*NE2 + gslot]     = packh(__expf(ta), __expf(tb));
            etI1[(size_t)h*2*NE2 + gslot + 4] = packh(__expf(0.2f*ta), __expf(0.2f*tb));
        }
    } else if (b < 1800) {
        int idx = (b - 72)*256 + tid;      // [0, 442368)
        int n = idx / 2304, c8 = idx % 2304;
        const float* ap = adj + (size_t)n*NE_ + c8*16;
        u32 o[8];
        #pragma unroll
        for (int q = 0; q < 4; q++) {
            float4 v = *(const float4*)(ap + q*4);
            o[2*q]   = packh(__expf(v.x), __expf(v.y));
            o[2*q+1] = packh(__expf(v.z), __expf(v.w));
        }
        u32* dst = eaP + (size_t)n*NE2 + c8*8;
        *(uint4*)(dst)     = make_uint4(o[0], o[1], o[2], o[3]);
        *(uint4*)(dst + 4) = make_uint4(o[4], o[5], o[6], o[7]);
    } else if (b == 1800) {
        for (int v = tid; v < 3072; v += 256) {
            int a = v >> 10, rem = v & 1023, h = rem >> 7, d = rem & 127;
            float w = 0.f;
            #pragma unroll
            for (int f = 0; f < 8; f++)
                w += wn1[(((size_t)a*NH + h)*128 + d)*8 + f] * aes1[h*8 + f];
            wt1[v] = w;
        }
    } else {
        int ah = b - 1801;
        int a = ah / NH, h = ah % NH;
        __shared__ float wt0[ND];
        if (tid < ND) {
            float w = 0.f;
            #pragma unroll
            for (int f = 0; f < 16; f++)
                w += wn0[(((size_t)a*NH + h)*ND + tid)*16 + f] * aes0[h*16 + f];
            wt0[tid] = w;
        }
        __syncthreads();
        if (tid < NN) {
            float s = 0.f;
            #pragma unroll
            for (int d = 0; d < ND; d++) s += X[tid*ND + d] * wt0[d];
            es0 [ah*NN + tid] = packh(__expf(s), __expf(s));
            es50[ah*NN + tid] = packh(__expf(0.2f*s), __expf(0.2f*s));
        }
    }
}

// ---------------- K1: e2n attention, fp16 pk-math + f16 MFMA + LDS-staged ea ----------------
template<int FE>
__global__ __launch_bounds__(512, 3) void k_att3(
    const u32* __restrict__ es_,   // [A][H][N] half2(es,es)
    const u32* __restrict__ es5_,  // [A][H][N]
    const u32* __restrict__ etI,   // [H][NE2/4 groups][8]: 4 et pairs + 4 et5 pairs
    const u32* __restrict__ feP,   // [H][FE][NE2]
    const u32* __restrict__ eaP,   // [N][NE2]
    float* __restrict__ part)      // [A][S][12][H][FE+1][16]
{
    constexpr int S = 64, EPB = NE_/S, TILES = EPB/32;   // EPB=576, TILES=18
    constexpr int EP2 = EPB/2;                            // 288 u32 per row
    constexpr int ROWP = EP2 + 4;                         // padded row
    constexpr size_t PA = (size_t)S*12*NH*(FE+1)*16;
    __shared__ u32 sea[16*ROWP];                          // 18.7 KB

    int h = threadIdx.x >> 6, lane = threadIdx.x & 63;
    int fr = lane & 15, kg = lane >> 4;
    int split = blockIdx.x, ntile = blockIdx.y;
    int nm = ntile*16 + fr;
    int p0 = split*EP2;

    // cooperative stage: 512 threads, 16 rows x 288 u32
    {
        int r = threadIdx.x >> 5, c0 = threadIdx.x & 31;
        const u32* src = eaP + (size_t)(ntile*16 + r)*NE2 + p0;
        #pragma unroll
        for (int i = 0; i < 9; i++)
            sea[r*ROWP + c0 + i*32] = src[c0 + i*32];
    }

    h2v esh[NBA], es5h[NBA];
    #pragma unroll
    for (int a = 0; a < NBA; a++) {
        esh[a]  = u2h(es_ [(a*NH + h)*NN + nm]);
        es5h[a] = u2h(es5_[(a*NH + h)*NN + nm]);
    }

    const u32* etg = etI + (size_t)h*2*NE2 + ((size_t)split*72 + kg)*8;
    const u32* fp  = feP + ((size_t)h*FE + (fr < FE ? fr : 0))*NE2 + p0 + kg*4;
    u32 bfill = (fr == FE) ? 0x3C003C00u : 0u;   // fp16 1.0 pair / 0
    uint4 bc = make_uint4(bfill, bfill, bfill, bfill);

    f32x4 acc[NBA];
    #pragma unroll
    for (int a = 0; a < NBA; a++) acc[a] = (f32x4){0.f, 0.f, 0.f, 0.f};

    __syncthreads();

    const u32* seap = sea + fr*ROWP + kg*4;
    #pragma unroll 2
    for (int t = 0; t < TILES; t++) {
        uint4 etq  = *(const uint4*)(etg + t*32);
        uint4 et5q = *(const uint4*)(etg + t*32 + 4);
        uint4 eaq  = *(const uint4*)(seap + t*16);
        uint4 bq = bc;
        if (fr < FE) bq = *(const uint4*)(fp + t*16);
        union { uint4 u; f16x8 v; } B; B.u = bq;

        u32 etw[4]  = {etq.x,  etq.y,  etq.z,  etq.w};
        u32 et5w[4] = {et5q.x, et5q.y, et5q.z, et5q.w};
        u32 eaw[4]  = {eaq.x,  eaq.y,  eaq.z,  eaq.w};
        h2v g1[4], g2[4];
        #pragma unroll
        for (int p = 0; p < 4; p++) {
            h2v ea = u2h(eaw[p]);
            g1[p] = u2h(etw[p])  * ea;
            g2[p] = u2h(et5w[p]) * ea;
        }
        #pragma unroll
        for (int a = 0; a < NBA; a++) {
            union { uint4 u; f16x8 v; } A;
            u32 aw[4];
            #pragma unroll
            for (int p = 0; p < 4; p++) {
                h2v wv = __builtin_elementwise_max(esh[a] * g1[p], es5h[a] * g2[p]);
                aw[p] = h2u(wv);
            }
            A.u = make_uint4(aw[0], aw[1], aw[2], aw[3]);
            acc[a] = __builtin_amdgcn_mfma_f32_16x16x32_f16(A.v, B.v, acc[a], 0, 0, 0);
        }
    }

    if (fr <= FE) {
        float* pp = part + ((((size_t)split*12 + ntile)*NH + h)*(FE+1) + fr)*16 + kg*4;
        #pragma unroll
        for (int a = 0; a < NBA; a++)
            *(f32x4*)(pp + (size_t)a*PA) = acc[a];
    }
}

// ---------------- K1b: coalesced reduction of part over S ----------------
template<int FE>
__global__ __launch_bounds__(256) void k_red(
    const float* __restrict__ part, float* __restrict__ red)
{
    constexpr int S = 64, W = (FE+1)*16;
    constexpr size_t SSTR = (size_t)12*NH*W;
    constexpr size_t PA = (size_t)S*SSTR;
    int nt = blockIdx.x >> 3, h = blockIdx.x & 7;
    int t = threadIdx.x;
    if (t >= NBA*W) return;
    int a = t / W, i = t % W;
    const float* pp = part + (size_t)a*PA + ((size_t)nt*NH + h)*W + i;
    float v = 0.f;
    #pragma unroll 8
    for (int s = 0; s < S; s++) v += pp[(size_t)s*SSTR];
    red[((size_t)a*96 + nt*8 + h)*W + i] = v;
}

// ---------------- K2: f2, s2, t2 from reduced partials (grid.y = attr) ----------------
template<int DIN, int F, int FE>
__global__ __launch_bounds__(256) void k_mid(
    const float* __restrict__ Xh, int xstride,
    const float* __restrict__ wn,   // [A][H][DIN][F]
    const float* __restrict__ be,   // [H][FE]
    const float* __restrict__ wct,  // [H][F+FE][F]
    const float* __restrict__ bct,  // [H][F]
    const float* __restrict__ asf,  // [A][H][F]
    const float* __restrict__ anf,  // [A][H][F]
    const float* __restrict__ red,  // [A][96][(FE+1)*16]
    float* __restrict__ f2,         // [A][H][N][16]
    float* __restrict__ s2, float* __restrict__ t2)
{
    constexpr int DCT = F + FE, W = (FE+1)*16;
    int n = blockIdx.x, attr = blockIdx.y;
    int h = threadIdx.x >> 5, lane = threadIdx.x & 31;
    const float* Xp = Xh + (size_t)attr*xstride;
    const float* wnp = wn + (size_t)attr*NH*DIN*F;
    float* f2p = f2 + (size_t)attr*NH*NN*16;
    float v = 0.f;
    if (lane <= FE)
        v = red[((size_t)attr*96 + (n>>4)*8 + h)*W + lane*16 + (n & 15)];
    float den = __shfl(v, FE, 32);
    float nfe = (lane < FE) ? v/den + be[h*FE+lane] : 0.f;
    float fv = 0.f;
    if (lane < F) {
        for (int d = 0; d < DIN; d++) fv += Xp[n*DIN+d] * wnp[(h*DIN+d)*F+lane];
    }
    __shared__ float c[NH][DCT];
    if (lane < F)  c[h][lane]     = fv;
    if (lane < FE) c[h][F + lane] = nfe;
    __syncthreads();
    float f2v = 0.f;
    if (lane < F) {
        f2v = bct[h*F+lane];
        #pragma unroll
        for (int d = 0; d < DCT; d++) f2v += c[h][d] * wct[(h*DCT+d)*F+lane];
        f2p[((size_t)h*NN + n)*16 + lane] = f2v;
    }
    float s2p = (lane < F) ? f2v * asf[attr*NH*F + h*F+lane] : 0.f;
    float t2p = (lane < F) ? f2v * anf[attr*NH*F + h*F+lane] : 0.f;
    #pragma unroll
    for (int m = 1; m < 32; m <<= 1) { s2p += __shfl_xor(s2p, m); t2p += __shfl_xor(t2p, m); }
    if (lane == 0) { s2[attr*NH*NN + h*NN+n] = s2p; t2[attr*NH*NN + h*NN+n] = t2p; }
}

// ---------------- K3: partial tE/cs over m-quarters (grid = (8, A, 4)) ----------------
__global__ __launch_bounds__(192) void k_te(
    const float* __restrict__ Einfo, size_t estride,
    const float* __restrict__ t2,
    float* __restrict__ tEp,   // [A][H][4][192]
    float* __restrict__ csp)   // [A][4][192]
{
    int h = blockIdx.x, attr = blockIdx.y, q = blockIdx.z, k = threadIdx.x;
    const float* Ep = Einfo + (size_t)attr*estride + (size_t)q*48*NN;
    const float* t2p = t2 + attr*NH*NN + h*NN + q*48;
    float a = 0.f, c = 0.f;
    #pragma unroll 8
    for (int m = 0; m < 48; m++) {
        float ev = Ep[m*NN + k];
        a += t2p[m] * ev;
        c += ev;
    }
    tEp[(((size_t)attr*NH + h)*4 + q)*NN + k] = a;
    if (h == 0) csp[((size_t)attr*4 + q)*NN + k] = c;
}

// ---------------- K4: att2 rows, nf, outputs (grid.y = attr); L0 also emits es1 ----------------
template<int F, int LAYER>
__global__ __launch_bounds__(256) void k_out(
    const float* __restrict__ A,    // [A][N][N]
    const float* __restrict__ s2,
    const float* __restrict__ tEp,  // [A][H][4][192]
    const float* __restrict__ csp,  // [A][4][192]
    const float* __restrict__ f2,   // [A][H][N][16]
    const float* __restrict__ bn,   // [A][H][F]
    const float* __restrict__ X,
    float* __restrict__ out,
    float* __restrict__ xh1, float* __restrict__ einfo,
    const float* __restrict__ wt1,  // [A][H][128]
    u32* __restrict__ es1, u32* __restrict__ es51)
{
    int n = blockIdx.x, attr = blockIdx.y;
    int h = threadIdx.x >> 5, lane = threadIdx.x & 31;
    const float* Aattr = A + (size_t)attr*NE_;
    const float* f2p = f2 + (size_t)attr*NH*NN*16;
    const float* tb = tEp + ((size_t)attr*NH + h)*4*NN;
    const float* cb = csp + (size_t)attr*4*NN;
    float s2h = s2[attr*NH*NN + h*NN + n];
    float z[6];
    #pragma unroll
    for (int c6 = 0; c6 < 6; c6++) {
        int k = lane + 32*c6;
        float tEv = (tb[k] + tb[NN + k]) + (tb[2*NN + k] + tb[3*NN + k]);
        float csv = (cb[k] + cb[NN + k]) + (cb[2*NN + k] + cb[3*NN + k]);
        float d2v = s2h * csv + tEv;
        z[c6] = fmaxf(d2v, 0.2f*d2v) + Aattr[n*NN + k];
    }
    float mx = z[0];
    #pragma unroll
    for (int c6 = 1; c6 < 6; c6++) mx = fmaxf(mx, z[c6]);
    #pragma unroll
    for (int m = 1; m < 32; m <<= 1) mx = fmaxf(mx, __shfl_xor(mx, m));
    float w[6], den = 0.f;
    #pragma unroll
    for (int c6 = 0; c6 < 6; c6++) { w[c6] = __expf(z[c6] - mx); den += w[c6]; }
    #pragma unroll
    for (int m = 1; m < 32; m <<= 1) den += __shfl_xor(den, m);
    __shared__ float attL[NH][NN];
    __shared__ float xrow[128];
    #pragma unroll
    for (int c6 = 0; c6 < 6; c6++) attL[h][lane + 32*c6] = w[c6];
    __syncthreads();
    float r = 0.f;
    if (lane < F) {
        for (int k = 0; k < NN; k++) r += attL[h][k] * f2p[((size_t)h*NN + k)*16 + lane];
        r = r/den + bn[attr*NH*F + h*F + lane];
        r = r > 0.f ? r : __expf(r) - 1.f;   // elu
        out[((size_t)n*NBA + attr)*OUTC + (LAYER == 0 ? 10 : 138) + h*F + lane] = r;
        if (LAYER == 0) {
            xh1[(size_t)attr*NN*128 + n*128 + h*16 + lane] = r;
            xrow[h*16 + lane] = r;
        }
    }
    if (LAYER == 0 && h == 7) {
        #pragma unroll
        for (int c6 = 0; c6 < 6; c6++)
            einfo[(size_t)attr*NE_ + n*NN + lane + 32*c6] = w[c6] / den;
    }
    if (LAYER == 0 && h == 0 && lane < ND)
        out[((size_t)n*NBA + attr)*OUTC + lane] = X[n*ND + lane];
    if (LAYER == 0) {
        __syncthreads();
        float sp = 0.f;
        const float* wp = wt1 + ((size_t)attr*NH + h)*128;
        #pragma unroll
        for (int q = 0; q < 4; q++) sp += xrow[lane*4+q] * wp[lane*4+q];
        #pragma unroll
        for (int m = 1; m < 32; m <<= 1) sp += __shfl_xor(sp, m);
        if (lane == 0) {
            es1 [(attr*NH + h)*NN + n] = packh(__expf(sp), __expf(sp));
            es51[(attr*NH + h)*NN + n] = packh(__expf(0.2f*sp), __expf(0.2f*sp));
        }
    }
}

extern "C" void kernel_launch(void* const* d_in, const int* in_sizes, int n_in,
                              void* d_out, int out_size, void* d_ws, size_t ws_size,
                              hipStream_t stream) {
    const float* X    = (const float*)d_in[0];
    const float* A    = (const float*)d_in[1];
    const float* E    = (const float*)d_in[2];
    const float* adj  = (const float*)d_in[3];
    const float* w_n0 = (const float*)d_in[4];
    const float* b_n0 = (const float*)d_in[5];
    const float* as0  = (const float*)d_in[6];
    const float* an0  = (const float*)d_in[7];
    const float* w_n1 = (const float*)d_in[8];
    const float* b_n1 = (const float*)d_in[9];
    const float* as1  = (const float*)d_in[10];
    const float* an1  = (const float*)d_in[11];
    const float* w_e0 = (const float*)d_in[12];
    const float* b_e0 = (const float*)d_in[13];
    const float* w_ct0= (const float*)d_in[14];
    const float* b_ct0= (const float*)d_in[15];
    const float* aes0 = (const float*)d_in[16];
    const float* aen0 = (const float*)d_in[17];
    const float* w_e1 = (const float*)d_in[18];
    const float* b_e1 = (const float*)d_in[19];
    const float* w_ct1= (const float*)d_in[20];
    const float* b_ct1= (const float*)d_in[21];
    const float* aes1 = (const float*)d_in[22];
    const float* aen1 = (const float*)d_in[23];

    float* w      = (float*)d_ws;
    u32* etI0  = (u32*)(w + OFF_ETI0);
    u32* etI1  = (u32*)(w + OFF_ETI1);
    u32* ft0P  = (u32*)(w + OFF_FT0P);
    u32* ft1P  = (u32*)(w + OFF_FT1P);
    u32* eaP   = (u32*)(w + OFF_EAP);
    float* xh1   = w + OFF_XH1;
    float* einfo = w + OFF_EINF;
    u32* es0   = (u32*)(w + OFF_ES0);
    u32* es50  = (u32*)(w + OFF_ES50);
    u32* es1   = (u32*)(w + OFF_ES1);
    u32* es51  = (u32*)(w + OFF_ES51);
    float* wt1   = w + OFF_WT1;
    float* part  = w + OFF_PART;
    float* red   = w + OFF_RED;
    float* f2    = w + OFF_F2;
    float* s2    = w + OFF_S2;
    float* t2    = w + OFF_T2;
    float* tEp   = w + OFF_TEP;
    float* csp   = w + OFF_CSP;
    float* out   = (float*)d_out;

    k_pre<<<dim3(1825), dim3(256), 0, stream>>>(
        E, adj, X, w_e0, aen0, w_e1, aen1, w_n0, aes0, w_n1, aes1,
        etI0, etI1, ft0P, ft1P, eaP, es0, es50, wt1);

    // ---- layer 0 ----
    k_att3<4><<<dim3(64,12), dim3(512), 0, stream>>>(
        es0, es50, etI0, ft0P, eaP, part);
    k_red<4><<<dim3(96), dim3(256), 0, stream>>>(part, red);
    k_mid<10,16,4><<<dim3(NN,NBA), dim3(256), 0, stream>>>(
        X, 0, w_n0, b_e0, w_ct0, b_ct0, as0, an0, red, f2, s2, t2);
    k_te<<<dim3(8,NBA,4), dim3(192), 0, stream>>>(E, (size_t)NE_, t2, tEp, csp);
    k_out<16,0><<<dim3(NN,NBA), dim3(256), 0, stream>>>(
        A, s2, tEp, csp, f2, b_n0, X, out, xh1, einfo, wt1, es1, es51);

    // ---- layer 1 ----
    k_att3<2><<<dim3(64,12), dim3(512), 0, stream>>>(
        es1, es51, etI1, ft1P, eaP, part);
    k_red<2><<<dim3(96), dim3(256), 0, stream>>>(part, red);
    k_mid<128,8,2><<<dim3(NN,NBA), dim3(256), 0, stream>>>(
        xh1, NN*128, w_n1, b_e1, w_ct1, b_ct1, as1, an1, red, f2, s2, t2);
    k_te<<<dim3(8,NBA,4), dim3(192), 0, stream>>>(einfo, (size_t)NE_, t2, tEp, csp);
    k_out<8,1><<<dim3(NN,NBA), dim3(256), 0, stream>>>(
        A, s2, tEp, csp, f2, b_n1, X, out, xh1, einfo, wt1, es1, es51);
}

// Round 13
// 94.869 us; speedup vs baseline: 1.3336x; 1.0504x over previous
//
#include <hip/hip_runtime.h>
#include <hip/hip_bf16.h>

#define NN 192
#define NBA 3
#define NH 8
#define ND 10
#define NE_ (NN*NN)          // 36864
#define NE2 (NE_/2)          // 18432
#define OUTC 202             // 10 + 8*16 + 8*8

typedef unsigned int u32;
typedef unsigned short u16;
typedef __attribute__((ext_vector_type(2))) _Float16 h2v;
typedef __attribute__((ext_vector_type(8))) _Float16 f16x8;
typedef __attribute__((ext_vector_type(4))) float f32x4;

// ---- workspace layout (float-sized slots) ----
static const size_t OFF_ETI0  = 0;                        // [8][2*NE2] u32: groups of 8 (4 et pairs, 4 et5 pairs)
static const size_t OFF_ETI1  = OFF_ETI0  + 294912;
static const size_t OFF_FT0P  = OFF_ETI1  + 294912;       // [8][4][NE2] u32 half2
static const size_t OFF_FT1P  = OFF_FT0P  + 589824;       // [8][2][NE2]
static const size_t OFF_EAP   = OFF_FT1P  + 294912;       // [192][NE2] u32 half2 exp(adj)
static const size_t OFF_XH1   = OFF_EAP   + 3538944;      // [3][192][128] f32
static const size_t OFF_EINF  = OFF_XH1   + 73728;        // [3][192][192]
static const size_t OFF_ES0   = OFF_EINF  + 110592;       // [3][8][192] u32 half2(es,es)
static const size_t OFF_ES50  = OFF_ES0   + 4608;
static const size_t OFF_ES1   = OFF_ES50  + 4608;
static const size_t OFF_ES51  = OFF_ES1   + 4608;
static const size_t OFF_WT1   = OFF_ES51  + 4608;         // [3][8][128] f32
static const size_t OFF_PART  = OFF_WT1   + 3072;         // [3][64][12][8][FE+1][16]
static const size_t OFF_RED   = OFF_PART  + 1474560;      // [3][96][80] reduced partials
static const size_t OFF_F2    = OFF_RED   + 23040;        // [3][8][192][16]
static const size_t OFF_S2    = OFF_F2    + 73728;
static const size_t OFF_T2    = OFF_S2    + 4608;
static const size_t OFF_TEP   = OFF_T2    + 4608;         // [3][8][4][192] partial tE
static const size_t OFF_CSP   = OFF_TEP   + 18432;        // [3][4][192]
// total ~6.84M floats ~27.4 MB

__device__ __forceinline__ u32 h2u(h2v h) { union { h2v h; u32 u; } c; c.h = h; return c.u; }
__device__ __forceinline__ h2v u2h(u32 u) { union { u32 u; h2v h; } c; c.u = u; return c.h; }
__device__ __forceinline__ u32 packh(float a, float b) {
    h2v h; h.x = (_Float16)a; h.y = (_Float16)b; return h2u(h);
}

// ---------------- K_PRE: all attr-independent preprocessing, one launch ----------------
__global__ __launch_bounds__(256) void k_pre(
    const float* __restrict__ E, const float* __restrict__ adj,
    const float* __restrict__ X,
    const float* __restrict__ we0, const float* __restrict__ aen0,
    const float* __restrict__ we1, const float* __restrict__ aen1,
    const float* __restrict__ wn0, const float* __restrict__ aes0,
    const float* __restrict__ wn1, const float* __restrict__ aes1,
    u32* __restrict__ etI0, u32* __restrict__ etI1,
    u32* __restrict__ ft0P, u32* __restrict__ ft1P,
    u32* __restrict__ eaP,
    u32* __restrict__ es0, u32* __restrict__ es50,
    float* __restrict__ wt1)
{
    int b = blockIdx.x, tid = threadIdx.x;
    if (b < 72) {
        __shared__ float w0s[96], a0s[32], w1s[512], a1s[16];
        for (int i = tid; i < 96;  i += 256) w0s[i] = we0[i];
        for (int i = tid; i < 32;  i += 256) a0s[i] = aen0[i];
        for (int i = tid; i < 512; i += 256) w1s[i] = we1[i];
        for (int i = tid; i < 16;  i += 256) a1s[i] = aen1[i];
        __syncthreads();
        int ep = b*256 + tid;            // e-pair index
        int gslot = ((ep >> 2) << 3) + (ep & 3);   // interleaved group slot
        int e0 = 2*ep;
        float2 E0 = *(const float2*)(E + e0);
        float2 E1 = *(const float2*)(E + NE_ + e0);
        float2 E2 = *(const float2*)(E + 2*NE_ + e0);
        float fa[32], fb[32];
        #pragma unroll
        for (int h = 0; h < 8; h++) {
            float ta = 0.f, tb = 0.f;
            #pragma unroll
            for (int f = 0; f < 4; f++) {
                float wa = w0s[h*12+f], wb = w0s[h*12+4+f], wc = w0s[h*12+8+f];
                float va = E0.x*wa + E1.x*wb + E2.x*wc;
                float vb = E0.y*wa + E1.y*wb + E2.y*wc;
                fa[h*4+f] = va; fb[h*4+f] = vb;
                ft0P[(size_t)(h*4+f)*NE2 + ep] = packh(va, vb);
                ta += va * a0s[h*4+f];
                tb += vb * a0s[h*4+f];
            }
            etI0[(size_t)h*2*NE2 + gslot]     = packh(__expf(ta), __expf(tb));
            etI0[(size_t)h*2*NE2 + gslot + 4] = packh(__expf(0.2f*ta), __expf(0.2f*tb));
        }
        #pragma unroll
        for (int h = 0; h < 8; h++) {
            float aa = 0.f, ba = 0.f, ab = 0.f, bb = 0.f;
            #pragma unroll
            for (int d = 0; d < 32; d++) {
                float w0 = w1s[(h*32+d)*2], w1 = w1s[(h*32+d)*2+1];
                aa += fa[d] * w0;  ba += fa[d] * w1;
                ab += fb[d] * w0;  bb += fb[d] * w1;
            }
            ft1P[(size_t)(h*2+0)*NE2 + ep] = packh(aa, ab);
            ft1P[(size_t)(h*2+1)*NE2 + ep] = packh(ba, bb);
            float ta = aa*a1s[h*2] + ba*a1s[h*2+1];
            float tb = ab*a1s[h*2] + bb*a1s[h*2+1];
            etI1[(size_t)h*2*NE2 + gslot]     = packh(__expf(ta), __expf(tb));
            etI1[(size_t)h*2*NE2 + gslot + 4] = packh(__expf(0.2f*ta), __expf(0.2f*tb));
        }
    } else if (b < 1800) {
        int idx = (b - 72)*256 + tid;      // [0, 442368)
        int n = idx / 2304, c8 = idx % 2304;
        const float* ap = adj + (size_t)n*NE_ + c8*16;
        u32 o[8];
        #pragma unroll
        for (int q = 0; q < 4; q++) {
            float4 v = *(const float4*)(ap + q*4);
            o[2*q]   = packh(__expf(v.x), __expf(v.y));
            o[2*q+1] = packh(__expf(v.z), __expf(v.w));
        }
        u32* dst = eaP + (size_t)n*NE2 + c8*8;
        *(uint4*)(dst)     = make_uint4(o[0], o[1], o[2], o[3]);
        *(uint4*)(dst + 4) = make_uint4(o[4], o[5], o[6], o[7]);
    } else if (b == 1800) {
        for (int v = tid; v < 3072; v += 256) {
            int a = v >> 10, rem = v & 1023, h = rem >> 7, d = rem & 127;
            float w = 0.f;
            #pragma unroll
            for (int f = 0; f < 8; f++)
                w += wn1[(((size_t)a*NH + h)*128 + d)*8 + f] * aes1[h*8 + f];
            wt1[v] = w;
        }
    } else {
        int ah = b - 1801;
        int a = ah / NH, h = ah % NH;
        __shared__ float wt0[ND];
        if (tid < ND) {
            float w = 0.f;
            #pragma unroll
            for (int f = 0; f < 16; f++)
                w += wn0[(((size_t)a*NH + h)*ND + tid)*16 + f] * aes0[h*16 + f];
            wt0[tid] = w;
        }
        __syncthreads();
        if (tid < NN) {
            float s = 0.f;
            #pragma unroll
            for (int d = 0; d < ND; d++) s += X[tid*ND + d] * wt0[d];
            es0 [ah*NN + tid] = packh(__expf(s), __expf(s));
            es50[ah*NN + tid] = packh(__expf(0.2f*s), __expf(0.2f*s));
        }
    }
}

// ---------------- K1: e2n attention, fp16 pk-math + f16 MFMA + LDS-staged ea ----------------
template<int FE>
__global__ __launch_bounds__(512, 3) void k_att3(
    const u32* __restrict__ es_,   // [A][H][N] half2(es,es)
    const u32* __restrict__ es5_,  // [A][H][N]
    const u32* __restrict__ etI,   // [H][NE2/4 groups][8]: 4 et pairs + 4 et5 pairs
    const u32* __restrict__ feP,   // [H][FE][NE2]
    const u32* __restrict__ eaP,   // [N][NE2]
    float* __restrict__ part)      // [A][S][12][H][FE+1][16]
{
    constexpr int S = 64, EPB = NE_/S, TILES = EPB/32;   // EPB=576, TILES=18
    constexpr int EP2 = EPB/2;                            // 288 u32 per row
    constexpr int ROWP = EP2 + 4;                         // padded row
    constexpr size_t PA = (size_t)S*12*NH*(FE+1)*16;
    __shared__ u32 sea[16*ROWP];                          // 18.7 KB

    int h = threadIdx.x >> 6, lane = threadIdx.x & 63;
    int fr = lane & 15, kg = lane >> 4;
    int split = blockIdx.x, ntile = blockIdx.y;
    int nm = ntile*16 + fr;
    int p0 = split*EP2;

    // cooperative stage: 512 threads, 16 rows x 288 u32
    {
        int r = threadIdx.x >> 5, c0 = threadIdx.x & 31;
        const u32* src = eaP + (size_t)(ntile*16 + r)*NE2 + p0;
        #pragma unroll
        for (int i = 0; i < 9; i++)
            sea[r*ROWP + c0 + i*32] = src[c0 + i*32];
    }

    h2v esh[NBA], es5h[NBA];
    #pragma unroll
    for (int a = 0; a < NBA; a++) {
        esh[a]  = u2h(es_ [(a*NH + h)*NN + nm]);
        es5h[a] = u2h(es5_[(a*NH + h)*NN + nm]);
    }

    const u32* etg = etI + (size_t)h*2*NE2 + ((size_t)split*72 + kg)*8;
    const u32* fp  = feP + ((size_t)h*FE + (fr < FE ? fr : 0))*NE2 + p0 + kg*4;
    u32 bfill = (fr == FE) ? 0x3C003C00u : 0u;   // fp16 1.0 pair / 0
    uint4 bc = make_uint4(bfill, bfill, bfill, bfill);

    f32x4 acc[NBA];
    #pragma unroll
    for (int a = 0; a < NBA; a++) acc[a] = (f32x4){0.f, 0.f, 0.f, 0.f};

    __syncthreads();

    const u32* seap = sea + fr*ROWP + kg*4;
    #pragma unroll 3
    for (int t = 0; t < TILES; t++) {
        uint4 etq  = *(const uint4*)(etg + t*32);
        uint4 et5q = *(const uint4*)(etg + t*32 + 4);
        uint4 eaq  = *(const uint4*)(seap + t*16);
        uint4 bq = bc;
        if (fr < FE) bq = *(const uint4*)(fp + t*16);
        union { uint4 u; f16x8 v; } B; B.u = bq;

        u32 etw[4]  = {etq.x,  etq.y,  etq.z,  etq.w};
        u32 et5w[4] = {et5q.x, et5q.y, et5q.z, et5q.w};
        u32 eaw[4]  = {eaq.x,  eaq.y,  eaq.z,  eaq.w};
        h2v g1[4], g2[4];
        #pragma unroll
        for (int p = 0; p < 4; p++) {
            h2v ea = u2h(eaw[p]);
            g1[p] = u2h(etw[p])  * ea;
            g2[p] = u2h(et5w[p]) * ea;
        }
        #pragma unroll
        for (int a = 0; a < NBA; a++) {
            union { uint4 u; f16x8 v; } A;
            u32 aw[4];
            #pragma unroll
            for (int p = 0; p < 4; p++) {
                h2v wv = __builtin_elementwise_max(esh[a] * g1[p], es5h[a] * g2[p]);
                aw[p] = h2u(wv);
            }
            A.u = make_uint4(aw[0], aw[1], aw[2], aw[3]);
            acc[a] = __builtin_amdgcn_mfma_f32_16x16x32_f16(A.v, B.v, acc[a], 0, 0, 0);
        }
    }

    if (fr <= FE) {
        float* pp = part + ((((size_t)split*12 + ntile)*NH + h)*(FE+1) + fr)*16 + kg*4;
        #pragma unroll
        for (int a = 0; a < NBA; a++)
            *(f32x4*)(pp + (size_t)a*PA) = acc[a];
    }
}

// ---------------- K1b: coalesced reduction of part over S ----------------
template<int FE>
__global__ __launch_bounds__(256) void k_red(
    const float* __restrict__ part, float* __restrict__ red)
{
    constexpr int S = 64, W = (FE+1)*16;
    constexpr size_t SSTR = (size_t)12*NH*W;
    constexpr size_t PA = (size_t)S*SSTR;
    int nt = blockIdx.x >> 3, h = blockIdx.x & 7;
    int t = threadIdx.x;
    if (t >= NBA*W) return;
    int a = t / W, i = t % W;
    const float* pp = part + (size_t)a*PA + ((size_t)nt*NH + h)*W + i;
    float v = 0.f;
    #pragma unroll 8
    for (int s = 0; s < S; s++) v += pp[(size_t)s*SSTR];
    red[((size_t)a*96 + nt*8 + h)*W + i] = v;
}

// ---------------- K2: f2, s2, t2 from reduced partials (grid.y = attr) ----------------
template<int DIN, int F, int FE>
__global__ __launch_bounds__(256) void k_mid(
    const float* __restrict__ Xh, int xstride,
    const float* __restrict__ wn,   // [A][H][DIN][F]
    const float* __restrict__ be,   // [H][FE]
    const float* __restrict__ wct,  // [H][F+FE][F]
    const float* __restrict__ bct,  // [H][F]
    const float* __restrict__ asf,  // [A][H][F]
    const float* __restrict__ anf,  // [A][H][F]
    const float* __restrict__ red,  // [A][96][(FE+1)*16]
    float* __restrict__ f2,         // [A][H][N][16]
    float* __restrict__ s2, float* __restrict__ t2)
{
    constexpr int DCT = F + FE, W = (FE+1)*16;
    int n = blockIdx.x, attr = blockIdx.y;
    int h = threadIdx.x >> 5, lane = threadIdx.x & 31;
    const float* Xp = Xh + (size_t)attr*xstride;
    const float* wnp = wn + (size_t)attr*NH*DIN*F;
    float* f2p = f2 + (size_t)attr*NH*NN*16;
    float v = 0.f;
    if (lane <= FE)
        v = red[((size_t)attr*96 + (n>>4)*8 + h)*W + lane*16 + (n & 15)];
    float den = __shfl(v, FE, 32);
    float nfe = (lane < FE) ? v/den + be[h*FE+lane] : 0.f;
    float fv = 0.f;
    if (lane < F) {
        for (int d = 0; d < DIN; d++) fv += Xp[n*DIN+d] * wnp[(h*DIN+d)*F+lane];
    }
    __shared__ float c[NH][DCT];
    if (lane < F)  c[h][lane]     = fv;
    if (lane < FE) c[h][F + lane] = nfe;
    __syncthreads();
    float f2v = 0.f;
    if (lane < F) {
        f2v = bct[h*F+lane];
        #pragma unroll
        for (int d = 0; d < DCT; d++) f2v += c[h][d] * wct[(h*DCT+d)*F+lane];
        f2p[((size_t)h*NN + n)*16 + lane] = f2v;
    }
    float s2p = (lane < F) ? f2v * asf[attr*NH*F + h*F+lane] : 0.f;
    float t2p = (lane < F) ? f2v * anf[attr*NH*F + h*F+lane] : 0.f;
    #pragma unroll
    for (int m = 1; m < 32; m <<= 1) { s2p += __shfl_xor(s2p, m); t2p += __shfl_xor(t2p, m); }
    if (lane == 0) { s2[attr*NH*NN + h*NN+n] = s2p; t2[attr*NH*NN + h*NN+n] = t2p; }
}

// ---------------- K3: partial tE/cs over m-quarters (grid = (8, A, 4)) ----------------
__global__ __launch_bounds__(192) void k_te(
    const float* __restrict__ Einfo, size_t estride,
    const float* __restrict__ t2,
    float* __restrict__ tEp,   // [A][H][4][192]
    float* __restrict__ csp)   // [A][4][192]
{
    int h = blockIdx.x, attr = blockIdx.y, q = blockIdx.z, k = threadIdx.x;
    const float* Ep = Einfo + (size_t)attr*estride + (size_t)q*48*NN;
    const float* t2p = t2 + attr*NH*NN + h*NN + q*48;
    float a = 0.f, c = 0.f;
    #pragma unroll 8
    for (int m = 0; m < 48; m++) {
        float ev = Ep[m*NN + k];
        a += t2p[m] * ev;
        c += ev;
    }
    tEp[(((size_t)attr*NH + h)*4 + q)*NN + k] = a;
    if (h == 0) csp[((size_t)attr*4 + q)*NN + k] = c;
}

// ---------------- K4: att2 rows, nf, outputs (grid.y = attr); L0 also emits es1 ----------------
// PV k-split: lane = q*F + f, q in [0, 32/F); each q covers NN/(32/F) k's; shfl combine.
template<int F, int LAYER>
__global__ __launch_bounds__(256) void k_out(
    const float* __restrict__ A,    // [A][N][N]
    const float* __restrict__ s2,
    const float* __restrict__ tEp,  // [A][H][4][192]
    const float* __restrict__ csp,  // [A][4][192]
    const float* __restrict__ f2,   // [A][H][N][16]
    const float* __restrict__ bn,   // [A][H][F]
    const float* __restrict__ X,
    float* __restrict__ out,
    float* __restrict__ xh1, float* __restrict__ einfo,
    const float* __restrict__ wt1,  // [A][H][128]
    u32* __restrict__ es1, u32* __restrict__ es51)
{
    constexpr int KS = 32 / F, KC = NN / KS;   // k-split count, chunk size
    int n = blockIdx.x, attr = blockIdx.y;
    int h = threadIdx.x >> 5, lane = threadIdx.x & 31;
    const float* Aattr = A + (size_t)attr*NE_;
    const float* f2p = f2 + (size_t)attr*NH*NN*16;
    const float* tb = tEp + ((size_t)attr*NH + h)*4*NN;
    const float* cb = csp + (size_t)attr*4*NN;
    float s2h = s2[attr*NH*NN + h*NN + n];
    float z[6];
    #pragma unroll
    for (int c6 = 0; c6 < 6; c6++) {
        int k = lane + 32*c6;
        float tEv = (tb[k] + tb[NN + k]) + (tb[2*NN + k] + tb[3*NN + k]);
        float csv = (cb[k] + cb[NN + k]) + (cb[2*NN + k] + cb[3*NN + k]);
        float d2v = s2h * csv + tEv;
        z[c6] = fmaxf(d2v, 0.2f*d2v) + Aattr[n*NN + k];
    }
    float mx = z[0];
    #pragma unroll
    for (int c6 = 1; c6 < 6; c6++) mx = fmaxf(mx, z[c6]);
    #pragma unroll
    for (int m = 1; m < 32; m <<= 1) mx = fmaxf(mx, __shfl_xor(mx, m));
    float w[6], den = 0.f;
    #pragma unroll
    for (int c6 = 0; c6 < 6; c6++) { w[c6] = __expf(z[c6] - mx); den += w[c6]; }
    #pragma unroll
    for (int m = 1; m < 32; m <<= 1) den += __shfl_xor(den, m);
    __shared__ float attL[NH][NN];
    __shared__ float xrow[128];
    #pragma unroll
    for (int c6 = 0; c6 < 6; c6++) attL[h][lane + 32*c6] = w[c6];
    __syncthreads();
    // PV: all 32 lanes active — lane = q*F + f, k in [q*KC, (q+1)*KC)
    int f = lane % F, q = lane / F;
    float r = 0.f;
    {
        const float* fp0 = f2p + ((size_t)h*NN + q*KC)*16 + f;
        const float* ap0 = &attL[h][q*KC];
        #pragma unroll 8
        for (int k = 0; k < KC; k++) r += ap0[k] * fp0[k*16];
    }
    #pragma unroll
    for (int m = F; m < 32; m <<= 1) r += __shfl_xor(r, m);
    if (lane < F) {
        r = r/den + bn[attr*NH*F + h*F + lane];
        r = r > 0.f ? r : __expf(r) - 1.f;   // elu
        out[((size_t)n*NBA + attr)*OUTC + (LAYER == 0 ? 10 : 138) + h*F + lane] = r;
        if (LAYER == 0) {
            xh1[(size_t)attr*NN*128 + n*128 + h*16 + lane] = r;
            xrow[h*16 + lane] = r;
        }
    }
    if (LAYER == 0 && h == 7) {
        #pragma unroll
        for (int c6 = 0; c6 < 6; c6++)
            einfo[(size_t)attr*NE_ + n*NN + lane + 32*c6] = w[c6] / den;
    }
    if (LAYER == 0 && h == 0 && lane < ND)
        out[((size_t)n*NBA + attr)*OUTC + lane] = X[n*ND + lane];
    if (LAYER == 0) {
        __syncthreads();
        float sp = 0.f;
        const float* wp = wt1 + ((size_t)attr*NH + h)*128;
        #pragma unroll
        for (int qq = 0; qq < 4; qq++) sp += xrow[lane*4+qq] * wp[lane*4+qq];
        #pragma unroll
        for (int m = 1; m < 32; m <<= 1) sp += __shfl_xor(sp, m);
        if (lane == 0) {
            es1 [(attr*NH + h)*NN + n] = packh(__expf(sp), __expf(sp));
            es51[(attr*NH + h)*NN + n] = packh(__expf(0.2f*sp), __expf(0.2f*sp));
        }
    }
}

extern "C" void kernel_launch(void* const* d_in, const int* in_sizes, int n_in,
                              void* d_out, int out_size, void* d_ws, size_t ws_size,
                              hipStream_t stream) {
    const float* X    = (const float*)d_in[0];
    const float* A    = (const float*)d_in[1];
    const float* E    = (const float*)d_in[2];
    const float* adj  = (const float*)d_in[3];
    const float* w_n0 = (const float*)d_in[4];
    const float* b_n0 = (const float*)d_in[5];
    const float* as0  = (const float*)d_in[6];
    const float* an0  = (const float*)d_in[7];
    const float* w_n1 = (const float*)d_in[8];
    const float* b_n1 = (const float*)d_in[9];
    const float* as1  = (const float*)d_in[10];
    const float* an1  = (const float*)d_in[11];
    const float* w_e0 = (const float*)d_in[12];
    const float* b_e0 = (const float*)d_in[13];
    const float* w_ct0= (const float*)d_in[14];
    const float* b_ct0= (const float*)d_in[15];
    const float* aes0 = (const float*)d_in[16];
    const float* aen0 = (const float*)d_in[17];
    const float* w_e1 = (const float*)d_in[18];
    const float* b_e1 = (const float*)d_in[19];
    const float* w_ct1= (const float*)d_in[20];
    const float* b_ct1= (const float*)d_in[21];
    const float* aes1 = (const float*)d_in[22];
    const float* aen1 = (const float*)d_in[23];

    float* w      = (float*)d_ws;
    u32* etI0  = (u32*)(w + OFF_ETI0);
    u32* etI1  = (u32*)(w + OFF_ETI1);
    u32* ft0P  = (u32*)(w + OFF_FT0P);
    u32* ft1P  = (u32*)(w + OFF_FT1P);
    u32* eaP   = (u32*)(w + OFF_EAP);
    float* xh1   = w + OFF_XH1;
    float* einfo = w + OFF_EINF;
    u32* es0   = (u32*)(w + OFF_ES0);
    u32* es50  = (u32*)(w + OFF_ES50);
    u32* es1   = (u32*)(w + OFF_ES1);
    u32* es51  = (u32*)(w + OFF_ES51);
    float* wt1   = w + OFF_WT1;
    float* part  = w + OFF_PART;
    float* red   = w + OFF_RED;
    float* f2    = w + OFF_F2;
    float* s2    = w + OFF_S2;
    float* t2    = w + OFF_T2;
    float* tEp   = w + OFF_TEP;
    float* csp   = w + OFF_CSP;
    float* out   = (float*)d_out;

    k_pre<<<dim3(1825), dim3(256), 0, stream>>>(
        E, adj, X, w_e0, aen0, w_e1, aen1, w_n0, aes0, w_n1, aes1,
        etI0, etI1, ft0P, ft1P, eaP, es0, es50, wt1);

    // ---- layer 0 ----
    k_att3<4><<<dim3(64,12), dim3(512), 0, stream>>>(
        es0, es50, etI0, ft0P, eaP, part);
    k_red<4><<<dim3(96), dim3(256), 0, stream>>>(part, red);
    k_mid<10,16,4><<<dim3(NN,NBA), dim3(256), 0, stream>>>(
        X, 0, w_n0, b_e0, w_ct0, b_ct0, as0, an0, red, f2, s2, t2);
    k_te<<<dim3(8,NBA,4), dim3(192), 0, stream>>>(E, (size_t)NE_, t2, tEp, csp);
    k_out<16,0><<<dim3(NN,NBA), dim3(256), 0, stream>>>(
        A, s2, tEp, csp, f2, b_n0, X, out, xh1, einfo, wt1, es1, es51);

    // ---- layer 1 ----
    k_att3<2><<<dim3(64,12), dim3(512), 0, stream>>>(
        es1, es51, etI1, ft1P, eaP, part);
    k_red<2><<<dim3(96), dim3(256), 0, stream>>>(part, red);
    k_mid<128,8,2><<<dim3(NN,NBA), dim3(256), 0, stream>>>(
        xh1, NN*128, w_n1, b_e1, w_ct1, b_ct1, as1, an1, red, f2, s2, t2);
    k_te<<<dim3(8,NBA,4), dim3(192), 0, stream>>>(einfo, (size_t)NE_, t2, tEp, csp);
    k_out<8,1><<<dim3(NN,NBA), dim3(256), 0, stream>>>(
        A, s2, tEp, csp, f2, b_n1, X, out, xh1, einfo, wt1, es1, es51);
}